// Round 3
// baseline (438.914 us; speedup 1.0000x reference)
//
#include <hip/hip_runtime.h>
#include <math.h>
#include <stdint.h>

#define H     256
#define K2    512
#define SDEC  2048
#define NTHR  256

typedef __attribute__((ext_vector_type(8))) short  short8;
typedef __attribute__((ext_vector_type(4))) float  f32x4;

__device__ __forceinline__ unsigned short f2bf(float f) {
  union { float f; unsigned int u; } c; c.f = f;
  unsigned int u = c.u;
  unsigned int r = u + 0x7fffu + ((u >> 16) & 1u);   // RNE
  return (unsigned short)(r >> 16);
}
__device__ __forceinline__ float bf2f(unsigned short h) {
  union { unsigned int u; float f; } c; c.u = ((unsigned int)h) << 16;
  return c.f;
}

// ---------------------------------------------------------------------------
// Prep: fused transposed weights (bf16):  WfT[n][k], k in [0,512)
//   WfT[n][k] = bf16( sum_j W1[k][j]*W2[256+j][n] + (k<256 ? W2[k][n] : 0) )
// ---------------------------------------------------------------------------
__global__ __launch_bounds__(256) void fuse_weights(
    const float* __restrict__ W1, const float* __restrict__ W2,
    unsigned short* __restrict__ wft) {
  __shared__ float As[64][65];
  __shared__ float Bs[64][65];
  const int t  = threadIdx.x;
  const int k0 = (blockIdx.x >> 2) * 64;
  const int n0 = (blockIdx.x & 3) * 64;
  const int lr = t >> 2;
  const int ls = t & 3;
  const int tk = t >> 4;
  const int tn = t & 15;

  float acc[4][4];
#pragma unroll
  for (int i = 0; i < 4; ++i)
#pragma unroll
    for (int c = 0; c < 4; ++c) acc[i][c] = 0.0f;

  for (int jt = 0; jt < 4; ++jt) {
    const int j0 = jt * 64;
    __syncthreads();
    const float* a_src = W1 + (size_t)(k0 + lr) * H + j0 + ls * 16;
    const float* b_src = W2 + (size_t)(H + j0 + lr) * H + n0 + ls * 16;
#pragma unroll
    for (int i = 0; i < 16; ++i) {
      As[lr][ls * 16 + i] = a_src[i];
      Bs[lr][ls * 16 + i] = b_src[i];
    }
    __syncthreads();
#pragma unroll 8
    for (int j = 0; j < 64; ++j) {
      float a[4], b[4];
#pragma unroll
      for (int i = 0; i < 4; ++i) a[i] = As[tk * 4 + i][j];
#pragma unroll
      for (int c = 0; c < 4; ++c) b[c] = Bs[j][tn * 4 + c];
#pragma unroll
      for (int i = 0; i < 4; ++i)
#pragma unroll
        for (int c = 0; c < 4; ++c) acc[i][c] += a[i] * b[c];
    }
  }

#pragma unroll
  for (int i = 0; i < 4; ++i) {
    const int k = k0 + tk * 4 + i;
#pragma unroll
    for (int c = 0; c < 4; ++c) {
      const int n = n0 + tn * 4 + c;
      float v = acc[i][c];
      if (k < H) v += W2[(size_t)k * H + n];
      wft[(size_t)n * K2 + k] = f2bf(v);
    }
  }
}

__global__ __launch_bounds__(256) void fuse_bias(
    const float* __restrict__ W2, const float* __restrict__ b1,
    const float* __restrict__ b2, float* __restrict__ biasf) {
  const int n = threadIdx.x;
  float acc = b2[n];
  for (int j = 0; j < H; ++j) acc += b1[j] * W2[(size_t)(H + j) * H + n];
  biasf[n] = acc;
}

// ---------------------------------------------------------------------------
// Prep: fp32 -> bf16 bulk convert (float4 in, 8B out, fully coalesced)
// ---------------------------------------------------------------------------
__global__ __launch_bounds__(256) void conv_bf16(
    const float* __restrict__ src, unsigned short* __restrict__ dst, int n4) {
  const int i = blockIdx.x * 256 + threadIdx.x;
  if (i < n4) {
    const float4 f = ((const float4*)src)[i];
    uint2 o;
    o.x = (unsigned int)f2bf(f.x) | ((unsigned int)f2bf(f.y) << 16);
    o.y = (unsigned int)f2bf(f.z) | ((unsigned int)f2bf(f.w) << 16);
    ((uint2*)dst)[i] = o;
  }
}

// ---------------------------------------------------------------------------
// Main: barrier-free K-loop. Block = 64 rows x 256 cols; wave = 64 rows x 64
// cols. A and B fragments loaded straight from global (bf16) as dwordx4;
// fully unrolled 16 half-K-steps x 16 MFMA. One __syncthreads (LN stats).
// ---------------------------------------------------------------------------
template <bool PRE>
__global__ __launch_bounds__(NTHR, 3) void syl_main(
    const float* __restrict__ cemb, const int* __restrict__ tal,
    const float* __restrict__ dec, const unsigned short* __restrict__ cembh,
    const unsigned short* __restrict__ dech,
    const unsigned short* __restrict__ wft, const float* __restrict__ biasf,
    const float* __restrict__ gamma, const float* __restrict__ beta,
    float* __restrict__ out) {

  __shared__ float stats[4][64][2];   // 2 KB

  const int t    = threadIdx.x;
  const int wave = t >> 6;
  const int lane = t & 63;
  const int quad = lane >> 4;
  const int l15  = lane & 15;
  const int row0 = blockIdx.x * 64;
  const int bidx = blockIdx.x >> 8;   // 256 blocks per batch (16384/64)

  // per-lane token rows + masks for the 4 m-tiles this lane touches
  int  tok[4];
  bool msk[4];
#pragma unroll
  for (int m = 0; m < 4; ++m) {
    const int ix = tal[row0 + m * 16 + l15];
    msk[m] = ix >= 0;
    tok[m] = ix < 0 ? 0 : (ix >= SDEC ? SDEC - 1 : ix);
  }

  f32x4 acc[4][4];
#pragma unroll
  for (int m = 0; m < 4; ++m)
#pragma unroll
    for (int n = 0; n < 4; ++n) acc[m][n] = (f32x4){0.f, 0.f, 0.f, 0.f};

  const short8 z8 = (short8)0;

#pragma unroll
  for (int ki = 0; ki < 8; ++ki) {
#pragma unroll
    for (int ks = 0; ks < 2; ++ks) {
      const int kk = ki * 64 + ks * 32;   // compile-time constant per unroll
      short8 af[4], bf[4];

      if (kk < H) {
        // char half
#pragma unroll
        for (int m = 0; m < 4; ++m) {
          if (PRE) {
            af[m] = *(const short8*)(cembh +
                     (size_t)(row0 + m * 16 + l15) * H + kk + quad * 8);
          } else {
            const float* p = cemb + (size_t)(row0 + m * 16 + l15) * H + kk + quad * 8;
            const float4 lo = *(const float4*)p;
            const float4 hi = *(const float4*)(p + 4);
            short8 a;
            a[0] = (short)f2bf(lo.x); a[1] = (short)f2bf(lo.y);
            a[2] = (short)f2bf(lo.z); a[3] = (short)f2bf(lo.w);
            a[4] = (short)f2bf(hi.x); a[5] = (short)f2bf(hi.y);
            a[6] = (short)f2bf(hi.z); a[7] = (short)f2bf(hi.w);
            af[m] = a;
          }
        }
      } else {
        // gathered token half (masked)
#pragma unroll
        for (int m = 0; m < 4; ++m) {
          if (PRE) {
            short8 a = *(const short8*)(dech +
                        (size_t)(bidx * SDEC + tok[m]) * H + (kk - H) + quad * 8);
            af[m] = msk[m] ? a : z8;
          } else {
            const float* p = dec + (size_t)(bidx * SDEC + tok[m]) * H + (kk - H) + quad * 8;
            const float4 lo = *(const float4*)p;
            const float4 hi = *(const float4*)(p + 4);
            short8 a;
            a[0] = (short)f2bf(lo.x); a[1] = (short)f2bf(lo.y);
            a[2] = (short)f2bf(lo.z); a[3] = (short)f2bf(lo.w);
            a[4] = (short)f2bf(hi.x); a[5] = (short)f2bf(hi.y);
            a[6] = (short)f2bf(hi.z); a[7] = (short)f2bf(hi.w);
            af[m] = msk[m] ? a : z8;
          }
        }
      }

#pragma unroll
      for (int n = 0; n < 4; ++n)
        bf[n] = *(const short8*)(wft +
                 (size_t)(wave * 64 + n * 16 + l15) * K2 + kk + quad * 8);

#pragma unroll
      for (int n = 0; n < 4; ++n)
#pragma unroll
        for (int m = 0; m < 4; ++m)
          acc[m][n] = __builtin_amdgcn_mfma_f32_16x16x32_bf16(
              af[m], bf[n], acc[m][n], 0, 0, 0);
    }
  }

  // ---- epilogue: bias + LN stats (one barrier) + LN/GELU/residual
  float bvals[4], gvals[4], betv[4];
#pragma unroll
  for (int n = 0; n < 4; ++n) {
    const int col = wave * 64 + n * 16 + l15;
    bvals[n] = biasf[col];
    gvals[n] = gamma[col];
    betv[n]  = beta[col];
  }
#pragma unroll
  for (int m = 0; m < 4; ++m)
#pragma unroll
    for (int n = 0; n < 4; ++n)
#pragma unroll
      for (int r = 0; r < 4; ++r) acc[m][n][r] += bvals[n];

#pragma unroll
  for (int m = 0; m < 4; ++m)
#pragma unroll
    for (int r = 0; r < 4; ++r) {
      float a = 0.f, b = 0.f;
#pragma unroll
      for (int n = 0; n < 4; ++n) {
        const float v = acc[m][n][r];
        a += v; b += v * v;
      }
#pragma unroll
      for (int d = 1; d < 16; d <<= 1) {   // reduce across l15 lanes
        a += __shfl_xor(a, d, 64);
        b += __shfl_xor(b, d, 64);
      }
      if (l15 == 0) {
        const int row = m * 16 + quad * 4 + r;
        stats[wave][row][0] = a;
        stats[wave][row][1] = b;
      }
    }
  __syncthreads();

#pragma unroll
  for (int m = 0; m < 4; ++m) {
#pragma unroll
    for (int r = 0; r < 4; ++r) {
      const int rloc = m * 16 + quad * 4 + r;
      const float a = stats[0][rloc][0] + stats[1][rloc][0] +
                      stats[2][rloc][0] + stats[3][rloc][0];
      const float b = stats[0][rloc][1] + stats[1][rloc][1] +
                      stats[2][rloc][1] + stats[3][rloc][1];
      const float mu   = a * (1.0f / 256.0f);
      const float var  = b * (1.0f / 256.0f) - mu * mu;
      const float rstd = rsqrtf(var + 1e-5f);

      const size_t grow = (size_t)row0 + rloc;
      const float* crow = cemb + grow * H;
      const unsigned short* chrow = cembh + grow * H;
      float* orow = out + grow * H;
#pragma unroll
      for (int n = 0; n < 4; ++n) {
        const int col = wave * 64 + n * 16 + l15;
        const float x = (acc[m][n][r] - mu) * rstd;
        const float y = x * gvals[n] + betv[n];
        const float g = 0.5f * y * (1.0f + erff(y * 0.70710678118654752f));
        const float res = PRE ? bf2f(chrow[col]) : crow[col];
        orow[col] = res + g;   // lane-contiguous scalar stores (clean WRITE)
      }
    }
  }
}

extern "C" void kernel_launch(void* const* d_in, const int* in_sizes, int n_in,
                              void* d_out, int out_size, void* d_ws, size_t ws_size,
                              hipStream_t stream) {
  const float* cemb  = (const float*)d_in[0];
  const int*   tal   = (const int*)d_in[1];
  const float* dec   = (const float*)d_in[2];
  const float* W1    = (const float*)d_in[3];
  const float* b1    = (const float*)d_in[4];
  const float* W2    = (const float*)d_in[5];
  const float* b2    = (const float*)d_in[6];
  const float* gamma = (const float*)d_in[7];
  const float* beta  = (const float*)d_in[8];
  float* out = (float*)d_out;

  const int rows  = in_sizes[0] / H;        // 131072
  const int ncemb = in_sizes[0];            // 33554432 floats
  const int ndec  = in_sizes[2];            // 4194304 floats

  // workspace layout
  unsigned short* wft  = (unsigned short*)d_ws;                   // 262144 B
  float* biasf = (float*)((char*)d_ws + 262144);                  // 1024 B
  unsigned short* cembh = (unsigned short*)((char*)d_ws + 263168);
  unsigned short* dech  = (unsigned short*)((char*)d_ws + 263168 + (size_t)ncemb * 2);
  const size_t need = 263168 + (size_t)ncemb * 2 + (size_t)ndec * 2;

  hipLaunchKernelGGL(fuse_weights, dim3(32), dim3(256), 0, stream, W1, W2, wft);
  hipLaunchKernelGGL(fuse_bias, dim3(1), dim3(256), 0, stream, W2, b1, b2, biasf);

  if (ws_size >= need) {
    hipLaunchKernelGGL(conv_bf16, dim3((ncemb / 4 + 255) / 256), dim3(256), 0,
                       stream, cemb, cembh, ncemb / 4);
    hipLaunchKernelGGL(conv_bf16, dim3((ndec / 4 + 255) / 256), dim3(256), 0,
                       stream, dec, dech, ndec / 4);
    hipLaunchKernelGGL((syl_main<true>), dim3(rows / 64), dim3(NTHR), 0, stream,
                       cemb, tal, dec, cembh, dech, wft, biasf, gamma, beta, out);
  } else {
    hipLaunchKernelGGL((syl_main<false>), dim3(rows / 64), dim3(NTHR), 0, stream,
                       cemb, tal, dec, (const unsigned short*)nullptr,
                       (const unsigned short*)nullptr, wft, biasf, gamma, beta, out);
  }
}